// Round 6
// baseline (214.584 us; speedup 1.0000x reference)
//
#include <hip/hip_runtime.h>

namespace {
constexpr int kB = 2;
constexpr int kH = 352;
constexpr int kW = 1216;
constexpr int kHW = kH * kW;        // 428032
constexpr int kN = kB * kHW;        // 856064
constexpr float kDmax = 80.0f;
constexpr float kEps = 1e-6f;
constexpr int kBlock = 256;         // step kernels
constexpr int kPrepBlk = 64;        // prep: 1 wave/block
}

typedef _Float16 half_t;
typedef __attribute__((ext_vector_type(4))) _Float16 half4;

// Module-owned workspace, fully rewritten from inputs on every launch.
__device__ half_t g_Wh[(size_t)48 * kN];  // merged weights, fp16, ch-major (~82 MB, L3-resident)
__device__ float  g_Q[kN];                // fp32 constant term
__device__ float  g_ping[kN];             // Dt ping buffer

// Async global->LDS copy, 4 B per lane (dest = wave-uniform base + lane*4).
__device__ __forceinline__ void gload_lds4(const float* g, float* l) {
    __builtin_amdgcn_global_load_lds(
        (const __attribute__((address_space(1))) void*)g,
        (__attribute__((address_space(3))) void*)l, 4, 0, 0);
}

// Merged-weight precompute.
// Rounds 2-5 all landed at ~120 us / ~2 TB/s: the compiler serializes strided
// REGISTER loads (1 outstanding/wave x 12 waves/CU x 256 B / 900 cy = 2.1 TB/s
// - the measured number). Fix: ZERO bulk register loads. All 90 channels go
// through global_load_lds (async, no VGPR results, vmcnt self-throttles at 63
// in flight = 16 KB/wave). 64-thread blocks: LDS 23 KB -> 7 blocks/CU -> ~115
// KB DMA in flight per CU (HBM saturation needs ~9 KB). Merge phase reads LDS
// (lane-contiguous, 2 lanes/bank = conflict-free).
__global__ __launch_bounds__(kPrepBlk) void prep_kernel(
    const float* __restrict__ D0, const float* __restrict__ DL,
    const float* __restrict__ ML, const float* __restrict__ A3,
    const float* __restrict__ A5, const float* __restrict__ A7,
    const float* __restrict__ SG, const float* __restrict__ AL)
{
    // channel slots: a7 0..48 | a5 49..73 | a3 74..82 | sg 83..85 | d0 86 | dl 87 | ml 88 | al 89
    __shared__ float sh[90 * kPrepBlk];   // 23040 B -> 7 blocks/CU
    int tid = threadIdx.x;
    int idx = blockIdx.x * kPrepBlk + tid;   // grid exact: kN % 64 == 0
    int b = idx / kHW;                        // kHW % 64 == 0: block is batch-uniform
    int rem = idx - b * kHW;

    const float* a3p = A3 + (size_t)b * 9 * kHW + rem;
    const float* a5p = A5 + (size_t)b * 25 * kHW + rem;
    const float* a7p = A7 + (size_t)b * 49 * kHW + rem;
    const float* sgp = SG + (size_t)b * 3 * kHW + rem;

#pragma unroll
    for (int c = 0; c < 49; ++c) gload_lds4(a7p + (size_t)c * kHW, &sh[c * kPrepBlk]);
#pragma unroll
    for (int c = 0; c < 25; ++c) gload_lds4(a5p + (size_t)c * kHW, &sh[(49 + c) * kPrepBlk]);
#pragma unroll
    for (int c = 0; c < 9; ++c)  gload_lds4(a3p + (size_t)c * kHW, &sh[(74 + c) * kPrepBlk]);
#pragma unroll
    for (int c = 0; c < 3; ++c)  gload_lds4(sgp + (size_t)c * kHW, &sh[(83 + c) * kPrepBlk]);
    gload_lds4(D0 + idx, &sh[86 * kPrepBlk]);
    gload_lds4(DL + idx, &sh[87 * kPrepBlk]);
    gload_lds4(ML + idx, &sh[88 * kPrepBlk]);
    gload_lds4(AL + idx, &sh[89 * kPrepBlk]);

    __syncthreads();   // drains vmcnt -> LDS valid

    float s3 = 0.f, s5 = 0.f, s7 = 0.f;
#pragma unroll
    for (int c = 0; c < 49; ++c) s7 += fabsf(sh[c * kPrepBlk + tid]);
#pragma unroll
    for (int c = 0; c < 25; ++c) s5 += fabsf(sh[(49 + c) * kPrepBlk + tid]);
#pragma unroll
    for (int c = 0; c < 9; ++c)  s3 += fabsf(sh[(74 + c) * kPrepBlk + tid]);

    float inv3 = 1.f / (s3 + kEps);
    float inv5 = 1.f / (s5 + kEps);
    float inv7 = 1.f / (s7 + kEps);

    float g0 = sh[83 * kPrepBlk + tid];
    float g1 = sh[84 * kPrepBlk + tid];
    float g2 = sh[85 * kPrepBlk + tid];
    float mx = fmaxf(g0, fmaxf(g1, g2));
    float e0 = expf(g0 - mx), e1 = expf(g1 - mx), e2 = expf(g2 - mx);
    float einv = 1.f / (e0 + e1 + e2);

    float d0 = sh[86 * kPrepBlk + tid];
    float dl = sh[87 * kPrepBlk + tid];
    float m  = (sh[88 * kPrepBlk + tid] > 0.5f) ? 1.f : 0.f;
    float al = fminf(fmaxf(sh[89 * kPrepBlk + tid], 0.f), 1.f);
    float g  = al * m;
    float omg = 1.f - g;

    float w3 = omg * e0 * einv * inv3;
    float w5 = omg * e1 * einv * inv5;
    float w7 = omg * e2 * einv * inv7;

    float c3 = sh[(74 + 4) * kPrepBlk + tid];
    float c5 = sh[(49 + 12) * kPrepBlk + tid];
    float c7 = sh[24 * kPrepBlk + tid];
    g_Q[idx] = (w3 * c3 + w5 * c5 + w7 * c7) * d0 + g * dl;

    int oi = 0;
#pragma unroll
    for (int i = 0; i < 49; ++i) {
        int dy = i / 7 - 3, dx = i % 7 - 3;
        if (dy == 0 && dx == 0) continue;    // center tap's Dt coef cancels
        float wv = w7 * sh[i * kPrepBlk + tid];
        if (dy >= -2 && dy <= 2 && dx >= -2 && dx <= 2)
            wv += w5 * sh[(49 + (dy + 2) * 5 + (dx + 2)) * kPrepBlk + tid];
        if (dy >= -1 && dy <= 1 && dx >= -1 && dx <= 1)
            wv += w3 * sh[(74 + (dy + 1) * 3 + (dx + 1)) * kPrepBlk + tid];
        g_Wh[(size_t)oi * kN + idx] = (half_t)wv;
        ++oi;
    }
}

// One propagation step, 4 pixels/thread (unchanged from round 4: ~13.3 us).
__global__ __launch_bounds__(kBlock) void step_kernel(
    const float* __restrict__ Din_ext, float* __restrict__ Dout_ext,
    int src_g, int dst_g)
{
    const float* Din = src_g ? g_ping : Din_ext;
    float* Dout = dst_g ? g_ping : Dout_ext;

    int t = blockIdx.x * kBlock + threadIdx.x;   // 0 .. kN/4-1
    int p = t * 4;
    int b = p / kHW;                             // kHW % 4 == 0
    int rem = p - b * kHW;
    int y = rem / kW;                            // kW % 4 == 0: stays in one row
    int x0 = rem - y * kW;
    const float* dinb = Din + (size_t)b * kHW;

    float4 q = *(const float4*)(&g_Q[p]);
    float acc[4] = {q.x, q.y, q.z, q.w};

    int oi = 0;
#pragma unroll
    for (int dy = -3; dy <= 3; ++dy) {
        int ny = y + dy;
        bool rv = (ny >= 0) && (ny < kH);
        if (!rv) { oi += (dy == 0) ? 6 : 7; continue; }   // zero contribution
        const float* dr = dinb + ny * kW;

        float rowv[12];   // covers x0-4 .. x0+7
#pragma unroll
        for (int s = 0; s < 3; ++s) {
            int xb = x0 + (s - 1) * 4;
            float4 v = (xb >= 0 && xb < kW) ? *(const float4*)(dr + xb)
                                            : make_float4(0.f, 0.f, 0.f, 0.f);
            rowv[s * 4 + 0] = v.x; rowv[s * 4 + 1] = v.y;
            rowv[s * 4 + 2] = v.z; rowv[s * 4 + 3] = v.w;
        }
#pragma unroll
        for (int dx = -3; dx <= 3; ++dx) {
            if (dy == 0 && dx == 0) continue;
            half4 w = *(const half4*)(&g_Wh[(size_t)oi * kN + p]);
#pragma unroll
            for (int j = 0; j < 4; ++j)
                acc[j] = fmaf((float)w[j], rowv[4 + j + dx], acc[j]);
            ++oi;
        }
    }

    float4 o;
    o.x = fminf(fmaxf(acc[0], 0.f), kDmax);
    o.y = fminf(fmaxf(acc[1], 0.f), kDmax);
    o.z = fminf(fmaxf(acc[2], 0.f), kDmax);
    o.w = fminf(fmaxf(acc[3], 0.f), kDmax);
    *(float4*)(&Dout[p]) = o;
}

extern "C" void kernel_launch(void* const* d_in, const int* in_sizes, int n_in,
                              void* d_out, int out_size, void* d_ws, size_t ws_size,
                              hipStream_t stream) {
    const float* D0 = (const float*)d_in[0];
    const float* DL = (const float*)d_in[1];
    const float* ML = (const float*)d_in[2];
    const float* A3 = (const float*)d_in[3];
    const float* A5 = (const float*)d_in[4];
    const float* A7 = (const float*)d_in[5];
    const float* SG = (const float*)d_in[6];
    const float* AL = (const float*)d_in[7];
    float* out = (float*)d_out;

    dim3 gridPrep(kN / kPrepBlk);      // 13376, exact
    dim3 gridStep(kN / 4 / kBlock);    // 836, exact

    prep_kernel<<<gridPrep, dim3(kPrepBlk), 0, stream>>>(D0, DL, ML, A3, A5, A7, SG, AL);

    // Chain: D0 -> ping -> out -> ping -> out -> ping -> out
    step_kernel<<<gridStep, dim3(kBlock), 0, stream>>>(D0, nullptr, 0, 1);
    step_kernel<<<gridStep, dim3(kBlock), 0, stream>>>(nullptr, out, 1, 0);
    step_kernel<<<gridStep, dim3(kBlock), 0, stream>>>(out, nullptr, 0, 1);
    step_kernel<<<gridStep, dim3(kBlock), 0, stream>>>(nullptr, out, 1, 0);
    step_kernel<<<gridStep, dim3(kBlock), 0, stream>>>(out, nullptr, 0, 1);
    step_kernel<<<gridStep, dim3(kBlock), 0, stream>>>(nullptr, out, 1, 0);
}